// Round 4
// baseline (1392.027 us; speedup 1.0000x reference)
//
#include <hip/hip_runtime.h>
#include <stdint.h>
#include <stddef.h>

#define NEGF (-1.0e30f)

typedef __attribute__((ext_vector_type(2))) _Float16 half2_t;
typedef uint32_t u32x16 __attribute__((ext_vector_type(16)));

constexpr int Bn = 32;
constexpr int Tn = 2000;
constexpr int Cn = 256;
constexpr int Un = 200;
constexpr int Sn = 2 * Un + 1;  // 401 extended states
constexpr float Kn = 4096.0f;   // den normalization target

__device__ __forceinline__ float fdot2f(uint32_t a, uint32_t b, float c) {
  half2_t ha = __builtin_bit_cast(half2_t, a);
  half2_t hb = __builtin_bit_cast(half2_t, b);
#if __has_builtin(__builtin_amdgcn_fdot2)
  return __builtin_amdgcn_fdot2(ha, hb, c, false);
#else
  return c + (float)ha.x * (float)hb.x + (float)ha.y * (float)hb.y;
#endif
}

template <int CTRL>
__device__ __forceinline__ float dppf(float x) {
#if __has_builtin(__builtin_amdgcn_update_dpp)
  int xi = __builtin_bit_cast(int, x);
  int y = __builtin_amdgcn_update_dpp(0, xi, CTRL, 0xF, 0xF, false);
  return __builtin_bit_cast(float, y);
#else
  return x;
#endif
}
#define dpp_x1(v) dppf<0xB1>(v)    // quad_perm(1,0,3,2): lane ^ 1
#define dpp_x2(v) dppf<0x4E>(v)    // quad_perm(2,3,0,1): lane ^ 2
#define dpp_x8(v) dppf<0x128>(v)   // row_ror:8 (16-lane row): lane ^ 8

// lane ^ 4 via ds_swizzle bit-mode: offset = (xor<<10)|(or<<5)|and = 0x101F
__device__ __forceinline__ float swz4f(float x) {
  int xi = __builtin_bit_cast(int, x);
  int y = __builtin_amdgcn_ds_swizzle(xi, 0x101F);
  return __builtin_bit_cast(float, y);
}

__device__ __forceinline__ uint32_t packe(float a, float b) {
  half2_t h;
  h.x = (_Float16)a;
  h.y = (_Float16)b;
  return __builtin_bit_cast(uint32_t, h);
}

__device__ __forceinline__ float lse3(float a, float b, float c) {
  float m = fmaxf(fmaxf(a, b), c);
  return m + __logf(__expf(a - m) + __expf(b - m) + __expf(c - m));
}

__device__ __forceinline__ int clampi(int v, int lo, int hi) {
  return v < lo ? lo : (v > hi ? hi : v);
}

// 64 blocks x 512 threads. Blocks [0,32): denominator. Blocks [32,64): CTC num.
// Den per-lane E tile = 64 dwords (4 x u32x16) + ~50 misc -> fits arch VGPRs at
// 2 waves/SIMD without allocator heroics (round-3: 128-dword tile forced AGPR
// residency -> +2.2x issue from accvgpr_read movs).
__global__ __launch_bounds__(512) void fwd_kernel(
    const float* __restrict__ logp, const int* __restrict__ targets,
    const int* __restrict__ in_lens, const int* __restrict__ tgt_lens,
    const float* __restrict__ trans, const float* __restrict__ start,
    float* __restrict__ ws) {
  const int tid = threadIdx.x;
  const int bid = blockIdx.x;

  if (bid < Bn) {
    // ============ denominator forward, exp domain, 16i x 8col tile ============
    const int b = bid;
    const int L = clampi(in_lens[b], Sn, Tn);
    const int q = tid & 15;   // i-chunk [16q, 16q+16)
    const int u = tid >> 4;   // column group: cols {u + 32k}
    const int b3 = (q >> 3) & 1, b2 = (q >> 2) & 1, b1 = (q >> 1) & 1;
    const int kown = 4 * b3 + 2 * b2 + b1;
    const int jown = u + 32 * kown;  // column this lane stores after the reduce

    // ea chunks at 48B stride (16B-aligned for b128; worst conflict 2-way=free)
    __shared__ __align__(16) char eaLDS[2 * 768];
    __shared__ float sred[8];

// E tile: 4 x u32x16 SSA vectors; vector kk holds cols 2kk (elems 0-7) and
// 2kk+1 (elems 8-15); elem m = f16 pair (i=16q+2m, 16q+2m+1).
#define EPAIR(k, m)                                                   \
  packe(__expf(trans[(16 * q + 2 * (m)) * Cn + (u + 32 * (k))]),      \
        __expf(trans[(16 * q + 2 * (m) + 1) * Cn + (u + 32 * (k))]))
#define COL8(k)                                                       \
  EPAIR(k, 0), EPAIR(k, 1), EPAIR(k, 2), EPAIR(k, 3),                 \
  EPAIR(k, 4), EPAIR(k, 5), EPAIR(k, 6), EPAIR(k, 7)
    u32x16 EV0 = (u32x16){COL8(0), COL8(1)};
    u32x16 EV1 = (u32x16){COL8(2), COL8(3)};
    u32x16 EV2 = (u32x16){COL8(4), COL8(5)};
    u32x16 EV3 = (u32x16){COL8(6), COL8(7)};
#undef COL8
#undef EPAIR

    const float* lpb = logp + (size_t)b * Tn * Cn;

    // t = 0: stored = K * exp(start + lp0); G carries the log scale.
    float G = -__logf(Kn);
    if (tid < Cn) {
      *(_Float16*)(eaLDS + 48 * (tid >> 4) + 2 * (tid & 15)) =
          (_Float16)(Kn * __expf(start[tid] + lpb[tid]));
    }
    // 2-deep emission pipeline for column jown: p_cur ready, lp_mid in flight.
    float p_cur = __expf(lpb[Cn + jown]);
    float lp_mid = lpb[2 * Cn + jown];
    __syncthreads();

    const uint32_t ONE2 = 0x3C003C00u;  // f16 (1.0, 1.0)
    const char* rchunk = eaLDS + 48 * q;
    char* wslot = eaLDS + 48 * (jown >> 4) + 2 * (jown & 15);

    for (int t = 1; t < L; ++t) {
      const int pr = (t - 1) & 1, pw = t & 1;

      const uint4* rb = (const uint4*)(rchunk + pr * 768);
      const uint4 r0 = rb[0], r1 = rb[1];

      // Z = Sigma ea (off critical chain: depends only on the reads)
      half2_t zp = (__builtin_bit_cast(half2_t, r0.x) + __builtin_bit_cast(half2_t, r0.y)) +
                   (__builtin_bit_cast(half2_t, r0.z) + __builtin_bit_cast(half2_t, r0.w));
      half2_t zq = (__builtin_bit_cast(half2_t, r1.x) + __builtin_bit_cast(half2_t, r1.y)) +
                   (__builtin_bit_cast(half2_t, r1.z) + __builtin_bit_cast(half2_t, r1.w));
      float zc = fdot2f(ONE2, __builtin_bit_cast(uint32_t, zp + zq), 0.f);
      zc += dpp_x1(zc);
      zc += dpp_x2(zc);
      zc += swz4f(zc);
      zc += dpp_x8(zc);  // total over all 16 chunks; uniform across the block
      const float invZ = Kn * __frcp_rn(zc);
      const float pm = p_cur * invZ;

      // 64 dot2: 8 columns x 8 ea dwords
      float c0 = 0.f, c1 = 0.f, c2 = 0.f, c3 = 0.f;
      float c4 = 0.f, c5 = 0.f, c6 = 0.f, c7 = 0.f;
#define DCOL(cv, V, base)                  \
  cv = fdot2f(V[(base) + 0], r0.x, cv);    \
  cv = fdot2f(V[(base) + 1], r0.y, cv);    \
  cv = fdot2f(V[(base) + 2], r0.z, cv);    \
  cv = fdot2f(V[(base) + 3], r0.w, cv);    \
  cv = fdot2f(V[(base) + 4], r1.x, cv);    \
  cv = fdot2f(V[(base) + 5], r1.y, cv);    \
  cv = fdot2f(V[(base) + 6], r1.z, cv);    \
  cv = fdot2f(V[(base) + 7], r1.w, cv);
      DCOL(c0, EV0, 0) DCOL(c1, EV0, 8)
      DCOL(c2, EV1, 0) DCOL(c3, EV1, 8)
      DCOL(c4, EV2, 0) DCOL(c5, EV2, 8)
      DCOL(c6, EV3, 0) DCOL(c7, EV3, 8)
#undef DCOL

      // reduce over the 16-lane q-group: 4-stage give/keep halving exchange
      float g, t0, t1, t2, t3, u0, u1, v0;
      g = b3 ? c0 : c4;  t0 = (b3 ? c4 : c0) + dpp_x8(g);
      g = b3 ? c1 : c5;  t1 = (b3 ? c5 : c1) + dpp_x8(g);
      g = b3 ? c2 : c6;  t2 = (b3 ? c6 : c2) + dpp_x8(g);
      g = b3 ? c3 : c7;  t3 = (b3 ? c7 : c3) + dpp_x8(g);
      g = b2 ? t0 : t2;  u0 = (b2 ? t2 : t0) + swz4f(g);
      g = b2 ? t1 : t3;  u1 = (b2 ? t3 : t1) + swz4f(g);
      g = b1 ? u0 : u1;  v0 = (b1 ? u1 : u0) + dpp_x2(g);
      const float s = v0 + dpp_x1(v0);  // both parity lanes hold col jown

      if ((q & 1) == 0) *(_Float16*)(wslot + pw * 768) = (_Float16)(s * pm);
      G -= __logf(invZ);

      // rotate the emission pipeline (load stays ~1 full step in flight)
      p_cur = __expf(lp_mid);
      const int tf = (t + 2 < L) ? t + 2 : L - 1;
      lp_mid = lpb[(size_t)tf * Cn + jown];
      __syncthreads();
    }

    // den[b] = G + log(Sigma_j stored_j)
    {
      const int pL = (L - 1) & 1;
      float e = 0.f;
      if (tid < Cn)
        e = (float)(*(const _Float16*)(eaLDS + pL * 768 + 48 * (tid >> 4) +
                                       2 * (tid & 15)));
#pragma unroll
      for (int off = 32; off >= 1; off >>= 1) e += __shfl_xor(e, off, 64);
      const int lane = tid & 63, wid = tid >> 6;
      if (lane == 0) sred[wid] = e;
      __syncthreads();
      if (tid == 0) {
        float ssum = ((sred[0] + sred[1]) + (sred[2] + sred[3])) +
                     ((sred[4] + sred[5]) + (sred[6] + sred[7]));
        ws[Bn + b] = G + __logf(ssum);
      }
    }
  } else {
    // ============ CTC numerator forward (log domain, 1 state/thread) ============
    const int b = bid - Bn;
    const int L = clampi(in_lens[b], Sn, Tn);
    const int tl = clampi(tgt_lens[b], 1, Un);

    __shared__ float abuf[2][Sn + 3];  // +2 front pad (NEG), states at [s+2]
    const float* lpb = logp + (size_t)b * Tn * Cn;
    const int* tgtb = targets + b * Un;

    const int s = tid;  // state id; lanes >= Sn idle but barrier-participate
    const bool act = (s < Sn);
    int e = 0;
    bool k = false;
    if (act && (s & 1)) {
      const int uu = (s - 1) >> 1;
      e = clampi(tgtb[uu], 1, Cn - 1);
      if (uu > 0) k = (e != clampi(tgtb[uu - 1], 1, Cn - 1));
    }

    // t = 0 init
    if (act) abuf[0][s + 2] = (s == 0) ? lpb[0] : (s == 1 ? lpb[e] : NEGF);
    if (tid < 2) { abuf[0][tid] = NEGF; abuf[1][tid] = NEGF; }
    // 2-deep emission pipeline (gather addresses are t-invariant)
    float em_cur = lpb[Cn + e];
    float em_mid = lpb[2 * Cn + e];
    __syncthreads();

    int cur = 0;
    for (int t = 1; t < L; ++t) {
      const float* A = abuf[cur];
      if (act) {
        const float x = A[s + 2], y = A[s + 1];
        const float z = k ? A[s] : NEGF;
        abuf[cur ^ 1][s + 2] = lse3(x, y, z) + em_cur;
      }
      em_cur = em_mid;
      const int tf = (t + 2 < L) ? t + 2 : L - 1;
      em_mid = lpb[(size_t)tf * Cn + e];
      __syncthreads();
      cur ^= 1;
    }
    if (tid == 0) {
      const int l = 2 * tl;
      const float x = abuf[cur][l + 2], y = abuf[cur][l + 1];
      const float m = fmaxf(x, y);
      ws[b] = m + __logf(__expf(x - m) + __expf(y - m));
    }
  }
}

__global__ void finalize_kernel(const float* __restrict__ ws,
                                float* __restrict__ out) {
  const int tid = threadIdx.x;  // 64 threads, one wave
  float tot = 0.f, cnt = 0.f;
  if (tid < Bn) {
    const float tv = ws[tid] - ws[Bn + tid];  // num - DEN_SCALE*den
    const bool valid = tv > 0.5f * NEGF;
    tot = valid ? tv : 0.f;
    cnt = valid ? 1.f : 0.f;
  }
#pragma unroll
  for (int off = 32; off >= 1; off >>= 1) {
    tot += __shfl_xor(tot, off, 64);
    cnt += __shfl_xor(cnt, off, 64);
  }
  if (tid == 0) out[0] = -tot / fmaxf(cnt, 1.f);
}

extern "C" void kernel_launch(void* const* d_in, const int* in_sizes, int n_in,
                              void* d_out, int out_size, void* d_ws, size_t ws_size,
                              hipStream_t stream) {
  const float* logp = (const float*)d_in[0];
  const int* targets = (const int*)d_in[1];
  const int* in_lens = (const int*)d_in[2];
  const int* tgt_lens = (const int*)d_in[3];
  const float* trans = (const float*)d_in[4];
  const float* start = (const float*)d_in[5];
  float* ws = (float*)d_ws;
  float* out = (float*)d_out;
  (void)in_sizes; (void)n_in; (void)out_size; (void)ws_size;

  fwd_kernel<<<dim3(2 * Bn), dim3(512), 0, stream>>>(
      logp, targets, in_lens, tgt_lens, trans, start, ws);
  finalize_kernel<<<dim3(1), dim3(64), 0, stream>>>(ws, out);
}